// Round 21
// baseline (371.698 us; speedup 1.0000x reference)
//
#include <hip/hip_runtime.h>
#include <hip/hip_bf16.h>
#include <cfloat>

// Problem constants
#define BB 8
#define TT 2048
#define CC 512
#define NNODE 1024

#define GAP_MARGIN 2e-4f  // screening margin (~40 sigma of bf16-split screen noise)
#define MAXC 6            // max rival candidates per flagged token
#define NSLOT 512         // recheck flag capacity

typedef float f32x4 __attribute__((ext_vector_type(4)));
typedef short bf16x8 __attribute__((ext_vector_type(8)));
typedef float float4v __attribute__((ext_vector_type(4)));
typedef unsigned short u16x4 __attribute__((ext_vector_type(4)));
typedef unsigned short u16x8 __attribute__((ext_vector_type(8)));

// ---------------------------------------------------------------------------
__device__ __forceinline__ unsigned fkey(float v) {
  unsigned u = __float_as_uint(v);
  return (u & 0x80000000u) ? ~u : (u | 0x80000000u);
}
__device__ __forceinline__ float fdec(unsigned k) {
  unsigned u = (k & 0x80000000u) ? (k & 0x7FFFFFFFu) : ~k;
  return __uint_as_float(u);
}
__device__ __forceinline__ unsigned short bf16_rn(float f) {
  unsigned u = __float_as_uint(f);
  u += 0x7FFFu + ((u >> 16) & 1u);
  return (unsigned short)(u >> 16);
}
__device__ __forceinline__ float bf16_tof(unsigned short h) {
  return __uint_as_float(((unsigned)h) << 16);
}

// ---------------------------------------------------------------------------
// Pre-split kernels: f32 -> bf16 hi (+ lo residual), vectorized x4.
// ---------------------------------------------------------------------------
__global__ __launch_bounds__(256) void split2_kernel(
    const float* __restrict__ src, unsigned short* __restrict__ hi,
    unsigned short* __restrict__ lo, long long n4) {
  long long i = (long long)blockIdx.x * 256 + threadIdx.x;
  long long stride = (long long)gridDim.x * 256;
  for (; i < n4; i += stride) {
    float4v v = ((const float4v*)src)[i];
    u16x4 h, l;
#pragma unroll
    for (int j = 0; j < 4; ++j) {
      unsigned short hh = bf16_rn(v[j]);
      h[j] = hh;
      l[j] = bf16_rn(v[j] - bf16_tof(hh));
    }
    ((u16x4*)hi)[i] = h;
    ((u16x4*)lo)[i] = l;
  }
}

__global__ __launch_bounds__(256) void split1_kernel(
    const float* __restrict__ src, unsigned short* __restrict__ hi, long long n4) {
  long long i = (long long)blockIdx.x * 256 + threadIdx.x;
  long long stride = (long long)gridDim.x * 256;
  for (; i < n4; i += stride) {
    float4v v = ((const float4v*)src)[i];
    u16x4 h;
#pragma unroll
    for (int j = 0; j < 4; ++j) h[j] = bf16_rn(v[j]);
    ((u16x4*)hi)[i] = h;
  }
}

// ---------------------------------------------------------------------------
// q GEMM K-SPLIT partial (pre-split inputs, 256 threads, 4 waves 2x2,
// 128x128 tile, BK=32): p[kp][b,m,n] = sum_{t in K half kp} Wq[m,t]*x[b,t,n].
// Grid (4 colblk x 2 kpart, NNODE/128, BB) = 512 blocks -> 2/CU.
// ---------------------------------------------------------------------------
__global__ __launch_bounds__(256) void mfma_q_part(
    const unsigned short* __restrict__ Wqh, const unsigned short* __restrict__ Wql,
    const unsigned short* __restrict__ xh, const unsigned short* __restrict__ xl,
    float* __restrict__ p0, float* __restrict__ p1) {
  __shared__ unsigned short Ah[128][40], Al[128][40], Bh[128][40], Bl[128][40];

  const int b = blockIdx.z;
  const unsigned short* xhb = xh + (size_t)b * TT * CC;
  const unsigned short* xlb = xl + (size_t)b * TT * CC;
  const int cb = blockIdx.x & 3;
  const int kp = blockIdx.x >> 2;
  const int m0 = blockIdx.y * 128;
  const int n0 = cb * 128;
  float* dst = kp ? p1 : p0;
  const int tid = threadIdx.x;
  const int l = tid & 63;
  const int wid = tid >> 6;
  const int wy = wid >> 1, wx = wid & 1;
  const int lrow = l & 15, lkb = (l >> 4) * 8;

  f32x4 acc[4][4] = {};

  const int kbeg = kp * (TT / 2), kend = kbeg + (TT / 2);
  for (int k0 = kbeg; k0 < kend; k0 += 32) {
#pragma unroll
    for (int p = 0; p < 2; ++p) {
      int idx = tid + p * 256;
      int ar = idx >> 2, ack = (idx & 3) * 8;
      *(u16x8*)&Ah[ar][ack] = *(const u16x8*)(Wqh + (size_t)(m0 + ar) * TT + k0 + ack);
      *(u16x8*)&Al[ar][ack] = *(const u16x8*)(Wql + (size_t)(m0 + ar) * TT + k0 + ack);
    }
#pragma unroll
    for (int p = 0; p < 2; ++p) {
      int idx = tid + p * 256;
      int nn = idx & 127, kq = idx >> 7;
      u16x8 hv, lv;
#pragma unroll
      for (int j = 0; j < 8; ++j) {
        size_t gi = (size_t)(k0 + kq * 8 + j) * CC + n0 + nn;
        hv[j] = xhb[gi];
        lv[j] = xlb[gi];
      }
      *(u16x8*)&Bh[nn][kq * 8] = hv;
      *(u16x8*)&Bl[nn][kq * 8] = lv;
    }
    __syncthreads();

    bf16x8 ah[4], al[4], bh[4], bl[4];
#pragma unroll
    for (int mf = 0; mf < 4; ++mf) {
      ah[mf] = *(const bf16x8*)&Ah[wy * 64 + mf * 16 + lrow][lkb];
      al[mf] = *(const bf16x8*)&Al[wy * 64 + mf * 16 + lrow][lkb];
    }
#pragma unroll
    for (int nf = 0; nf < 4; ++nf) {
      bh[nf] = *(const bf16x8*)&Bh[wx * 64 + nf * 16 + lrow][lkb];
      bl[nf] = *(const bf16x8*)&Bl[wx * 64 + nf * 16 + lrow][lkb];
    }
#pragma unroll
    for (int mf = 0; mf < 4; ++mf)
#pragma unroll
      for (int nf = 0; nf < 4; ++nf) {
        acc[mf][nf] =
            __builtin_amdgcn_mfma_f32_16x16x32_bf16(ah[mf], bh[nf], acc[mf][nf], 0, 0, 0);
        acc[mf][nf] =
            __builtin_amdgcn_mfma_f32_16x16x32_bf16(ah[mf], bl[nf], acc[mf][nf], 0, 0, 0);
        acc[mf][nf] =
            __builtin_amdgcn_mfma_f32_16x16x32_bf16(al[mf], bh[nf], acc[mf][nf], 0, 0, 0);
      }
    __syncthreads();
  }

#pragma unroll
  for (int mf = 0; mf < 4; ++mf)
#pragma unroll
    for (int r = 0; r < 4; ++r) {
      int m = m0 + wy * 64 + mf * 16 + (l >> 4) * 4 + r;
#pragma unroll
      for (int nf = 0; nf < 4; ++nf) {
        int n = n0 + wx * 64 + nf * 16 + lrow;
        dst[((size_t)b * NNODE + m) * CC + n] = acc[mf][nf][r];
      }
    }
}

// qadd: q = p0 + p1 + bq[m]; write bf16-split qh/ql. Vectorized x4.
__global__ __launch_bounds__(256) void qadd_kernel(
    const float* __restrict__ p0, const float* __restrict__ p1,
    const float* __restrict__ bq,
    unsigned short* __restrict__ qh, unsigned short* __restrict__ ql) {
  size_t i4 = (size_t)blockIdx.x * 256 + threadIdx.x;  // float4 index
  float4v a = ((const float4v*)p0)[i4];
  float4v c = ((const float4v*)p1)[i4];
  int m = (int)(((i4 * 4) / CC) & (NNODE - 1));
  float bias = bq[m];
  u16x4 h, l;
#pragma unroll
  for (int j = 0; j < 4; ++j) {
    float v = a[j] + c[j] + bias;
    unsigned short hh = bf16_rn(v);
    h[j] = hh;
    l[j] = bf16_rn(v - bf16_tof(hh));
  }
  ((u16x4*)qh)[i4] = h;
  ((u16x4*)ql)[i4] = l;
}

// ---------------------------------------------------------------------------
// Fused k (split) + v (plain) projection (256 threads, 64 tokens x 128 dims).
// Grid (CC/128, TT/64, BB) = 1024 blocks.
// ---------------------------------------------------------------------------
__global__ __launch_bounds__(256) void mfma_kv_pre(
    const unsigned short* __restrict__ xh, const unsigned short* __restrict__ xl,
    const unsigned short* __restrict__ Wkh, const unsigned short* __restrict__ Wkl,
    const unsigned short* __restrict__ Wvh,
    unsigned short* __restrict__ kh, unsigned short* __restrict__ kl,
    unsigned short* __restrict__ vout) {
  __shared__ unsigned short Ah[64][40], Al[64][40], Bkh[128][40], Bkl[128][40],
      Bvh[128][40];

  const int b = blockIdx.z;
  const unsigned short* xhb = xh + (size_t)b * TT * CC;
  const unsigned short* xlb = xl + (size_t)b * TT * CC;
  const int m0 = blockIdx.y * 64;
  const int n0 = blockIdx.x * 128;
  const int tid = threadIdx.x;
  const int l = tid & 63;
  const int wid = tid >> 6;
  const int wy = wid >> 1, wx = wid & 1;
  const int lrow = l & 15, lkb = (l >> 4) * 8;
  const int rr = tid >> 2, cq = tid & 3;

  f32x4 acck[2][4] = {}, accv[2][4] = {};

  for (int k0 = 0; k0 < CC; k0 += 32) {
    *(u16x8*)&Ah[rr][cq * 8] = *(const u16x8*)(xhb + (size_t)(m0 + rr) * CC + k0 + cq * 8);
    *(u16x8*)&Al[rr][cq * 8] = *(const u16x8*)(xlb + (size_t)(m0 + rr) * CC + k0 + cq * 8);
#pragma unroll
    for (int p = 0; p < 2; ++p) {
      int idx = tid + p * 256;
      int r = idx >> 2, ck = (idx & 3) * 8;
      *(u16x8*)&Bkh[r][ck] = *(const u16x8*)(Wkh + (size_t)(n0 + r) * CC + k0 + ck);
      *(u16x8*)&Bkl[r][ck] = *(const u16x8*)(Wkl + (size_t)(n0 + r) * CC + k0 + ck);
      *(u16x8*)&Bvh[r][ck] = *(const u16x8*)(Wvh + (size_t)(n0 + r) * CC + k0 + ck);
    }
    __syncthreads();

    bf16x8 ah[2], al[2], bkh4[4], bkl4[4], bvh4[4];
#pragma unroll
    for (int mf = 0; mf < 2; ++mf) {
      ah[mf] = *(const bf16x8*)&Ah[wy * 32 + mf * 16 + lrow][lkb];
      al[mf] = *(const bf16x8*)&Al[wy * 32 + mf * 16 + lrow][lkb];
    }
#pragma unroll
    for (int nf = 0; nf < 4; ++nf) {
      bkh4[nf] = *(const bf16x8*)&Bkh[wx * 64 + nf * 16 + lrow][lkb];
      bkl4[nf] = *(const bf16x8*)&Bkl[wx * 64 + nf * 16 + lrow][lkb];
      bvh4[nf] = *(const bf16x8*)&Bvh[wx * 64 + nf * 16 + lrow][lkb];
    }
#pragma unroll
    for (int mf = 0; mf < 2; ++mf)
#pragma unroll
      for (int nf = 0; nf < 4; ++nf) {
        acck[mf][nf] =
            __builtin_amdgcn_mfma_f32_16x16x32_bf16(ah[mf], bkh4[nf], acck[mf][nf], 0, 0, 0);
        acck[mf][nf] =
            __builtin_amdgcn_mfma_f32_16x16x32_bf16(ah[mf], bkl4[nf], acck[mf][nf], 0, 0, 0);
        acck[mf][nf] =
            __builtin_amdgcn_mfma_f32_16x16x32_bf16(al[mf], bkh4[nf], acck[mf][nf], 0, 0, 0);
        accv[mf][nf] =
            __builtin_amdgcn_mfma_f32_16x16x32_bf16(ah[mf], bvh4[nf], accv[mf][nf], 0, 0, 0);
      }
    __syncthreads();
  }

#pragma unroll
  for (int mf = 0; mf < 2; ++mf)
#pragma unroll
    for (int r = 0; r < 4; ++r) {
      int m = m0 + wy * 32 + mf * 16 + (l >> 4) * 4 + r;
#pragma unroll
      for (int nf = 0; nf < 4; ++nf) {
        int n = n0 + wx * 64 + nf * 16 + lrow;
        size_t off = ((size_t)b * TT + m) * CC + n;
        float kvv = acck[mf][nf][r];
        unsigned short h = bf16_rn(kvv);
        kh[off] = h;
        kl[off] = bf16_rn(kvv - bf16_tof(h));
        vout[off] = bf16_rn(accv[mf][nf][r]);
      }
    }
}

// ---------------------------------------------------------------------------
// sim (pre-split q,k; no store) + top-3 candidates. 128 nodes x 64 tokens.
// Epilogue: per-thread sorted local top-3 (fkey computed once per element);
// exactly equivalent to the 3-pass exclusion scheme (nodes distinct/thread).
// ---------------------------------------------------------------------------
__global__ __launch_bounds__(256) void mfma_sim_pre(
    const unsigned short* __restrict__ qh, const unsigned short* __restrict__ ql,
    const unsigned short* __restrict__ kh, const unsigned short* __restrict__ kl,
    unsigned long long* __restrict__ cand1, unsigned long long* __restrict__ cand2,
    unsigned long long* __restrict__ cand3) {
  __shared__ unsigned short Ah[128][40], Al[128][40], Bh[64][40], Bl[64][40];
  __shared__ unsigned long long c1[64], c2[64], c3[64];

  const int b = blockIdx.z;
  const unsigned short* qhb = qh + (size_t)b * NNODE * CC;
  const unsigned short* qlb = ql + (size_t)b * NNODE * CC;
  const unsigned short* khb = kh + (size_t)b * TT * CC;
  const unsigned short* klb = kl + (size_t)b * TT * CC;
  const int n0 = blockIdx.y * 128;  // nodes
  const int t0 = blockIdx.x * 64;   // tokens
  const int tid = threadIdx.x;
  const int l = tid & 63;
  const int wid = tid >> 6;
  const int wy = wid >> 1, wx = wid & 1;
  const int lrow = l & 15, lkb = (l >> 4) * 8;
  const int br = tid >> 2, bck = (tid & 3) * 8;

  if (tid < 64) { c1[tid] = 0ULL; c2[tid] = 0ULL; c3[tid] = 0ULL; }

  f32x4 acc[4][2] = {};

  for (int k0 = 0; k0 < CC; k0 += 32) {
#pragma unroll
    for (int p = 0; p < 2; ++p) {
      int idx = tid + p * 256;
      int r = idx >> 2, ck = (idx & 3) * 8;
      *(u16x8*)&Ah[r][ck] = *(const u16x8*)(qhb + (size_t)(n0 + r) * CC + k0 + ck);
      *(u16x8*)&Al[r][ck] = *(const u16x8*)(qlb + (size_t)(n0 + r) * CC + k0 + ck);
    }
    if (br < 64) {
      *(u16x8*)&Bh[br][bck] = *(const u16x8*)(khb + (size_t)(t0 + br) * CC + k0 + bck);
      *(u16x8*)&Bl[br][bck] = *(const u16x8*)(klb + (size_t)(t0 + br) * CC + k0 + bck);
    }
    __syncthreads();

    bf16x8 ah[4], al[4], bh[2], bl[2];
#pragma unroll
    for (int mf = 0; mf < 4; ++mf) {
      ah[mf] = *(const bf16x8*)&Ah[wy * 64 + mf * 16 + lrow][lkb];
      al[mf] = *(const bf16x8*)&Al[wy * 64 + mf * 16 + lrow][lkb];
    }
#pragma unroll
    for (int nf = 0; nf < 2; ++nf) {
      bh[nf] = *(const bf16x8*)&Bh[wx * 32 + nf * 16 + lrow][lkb];
      bl[nf] = *(const bf16x8*)&Bl[wx * 32 + nf * 16 + lrow][lkb];
    }
#pragma unroll
    for (int mf = 0; mf < 4; ++mf)
#pragma unroll
      for (int nf = 0; nf < 2; ++nf) {
        acc[mf][nf] =
            __builtin_amdgcn_mfma_f32_16x16x32_bf16(ah[mf], bh[nf], acc[mf][nf], 0, 0, 0);
        acc[mf][nf] =
            __builtin_amdgcn_mfma_f32_16x16x32_bf16(ah[mf], bl[nf], acc[mf][nf], 0, 0, 0);
        acc[mf][nf] =
            __builtin_amdgcn_mfma_f32_16x16x32_bf16(al[mf], bh[nf], acc[mf][nf], 0, 0, 0);
      }
    __syncthreads();
  }

  const float scl = 0.04419417382415922f;
  // Per-thread sorted local top-3 per token column (fkey once per element).
  unsigned long long L1[2], L2[2], L3[2];
#pragma unroll
  for (int nf = 0; nf < 2; ++nf) {
    L1[nf] = 0ULL; L2[nf] = 0ULL; L3[nf] = 0ULL;
#pragma unroll
    for (int mf = 0; mf < 4; ++mf)
#pragma unroll
      for (int r = 0; r < 4; ++r) {
        unsigned node = (unsigned)(n0 + wy * 64 + mf * 16 + (l >> 4) * 4 + r);
        unsigned long long pk =
            ((unsigned long long)fkey(acc[mf][nf][r] * scl) << 32) | node;
        if (pk > L1[nf]) {
          L3[nf] = L2[nf]; L2[nf] = L1[nf]; L1[nf] = pk;
        } else if (pk > L2[nf]) {
          L3[nf] = L2[nf]; L2[nf] = pk;
        } else if (pk > L3[nf]) {
          L3[nf] = pk;
        }
      }
  }
  // phase 1: block top-1
#pragma unroll
  for (int nf = 0; nf < 2; ++nf)
    atomicMax(&c1[wx * 32 + nf * 16 + lrow], L1[nf]);
  __syncthreads();
  // phase 2: best local excluding winner node (within local top-2)
#pragma unroll
  for (int nf = 0; nf < 2; ++nf) {
    int tcol = wx * 32 + nf * 16 + lrow;
    unsigned w1 = (unsigned)c1[tcol];
    unsigned long long m = ((unsigned)L1[nf] != w1) ? L1[nf] : L2[nf];
    if (m) atomicMax(&c2[tcol], m);
  }
  __syncthreads();
  // phase 3: best local excluding w1,w2 (within local top-3)
#pragma unroll
  for (int nf = 0; nf < 2; ++nf) {
    int tcol = wx * 32 + nf * 16 + lrow;
    unsigned w1 = (unsigned)c1[tcol];
    unsigned w2 = (unsigned)c2[tcol];
    unsigned long long m;
    unsigned n1 = (unsigned)L1[nf], n2 = (unsigned)L2[nf];
    if (n1 != w1 && n1 != w2) m = L1[nf];
    else if (n2 != w1 && n2 != w2) m = L2[nf];
    else m = L3[nf];
    if (m) atomicMax(&c3[tcol], m);
  }
  __syncthreads();
  if (tid < 64) {
    size_t base = ((size_t)b * TT + (t0 + tid)) * 8 + blockIdx.y;
    cand1[base] = c1[tid];
    cand2[base] = c2[tid];
    cand3[base] = c3[tid];
  }
}

// ---------------------------------------------------------------------------
// Wout GEMM (f32 inputs, plain bf16 MFMA, 256 threads, 64x64 tile).
// ---------------------------------------------------------------------------
__global__ __launch_bounds__(256) void mfma_wout(
    const float* __restrict__ A, const float* __restrict__ Bm,
    float* __restrict__ Cp, const float* __restrict__ bias) {
  __shared__ unsigned short Ah[64][40], Bh[64][40];
  const int m0 = blockIdx.y * 64;
  const int n0 = blockIdx.x * 64;
  const int tid = threadIdx.x;
  const int l = tid & 63;
  const int wid = tid >> 6;
  const int wy = wid >> 1, wx = wid & 1;
  const int lrow = l & 15, lkb = (l >> 4) * 8;

  f32x4 acc[2][2] = {};

  for (int k0 = 0; k0 < CC; k0 += 32) {
#pragma unroll
    for (int p = 0; p < 2; ++p) {
      int idx = tid + p * 256;
      int r = idx >> 3, c = (idx & 7) * 4;
      float4v va = *(const float4v*)(A + (size_t)(m0 + r) * CC + k0 + c);
      float4v vb = *(const float4v*)(Bm + (size_t)(n0 + r) * CC + k0 + c);
#pragma unroll
      for (int i = 0; i < 4; ++i) {
        Ah[r][c + i] = bf16_rn(va[i]);
        Bh[r][c + i] = bf16_rn(vb[i]);
      }
    }
    __syncthreads();

    bf16x8 ah[2], bh[2];
#pragma unroll
    for (int mf = 0; mf < 2; ++mf)
      ah[mf] = *(const bf16x8*)&Ah[wy * 32 + mf * 16 + lrow][lkb];
#pragma unroll
    for (int nf = 0; nf < 2; ++nf)
      bh[nf] = *(const bf16x8*)&Bh[wx * 32 + nf * 16 + lrow][lkb];
#pragma unroll
    for (int mf = 0; mf < 2; ++mf)
#pragma unroll
      for (int nf = 0; nf < 2; ++nf)
        acc[mf][nf] =
            __builtin_amdgcn_mfma_f32_16x16x32_bf16(ah[mf], bh[nf], acc[mf][nf], 0, 0, 0);
    __syncthreads();
  }

#pragma unroll
  for (int mf = 0; mf < 2; ++mf)
#pragma unroll
    for (int r = 0; r < 4; ++r) {
      int m = m0 + wy * 32 + mf * 16 + (l >> 4) * 4 + r;
#pragma unroll
      for (int nf = 0; nf < 2; ++nf) {
        int n = n0 + wx * 32 + nf * 16 + lrow;
        Cp[(size_t)m * CC + n] = acc[mf][nf][r] + bias[n];
      }
    }
}

__global__ __launch_bounds__(256) void fill_zero(unsigned* __restrict__ p, long long n) {
  long long i = (long long)blockIdx.x * 256 + threadIdx.x;
  long long stride = (long long)gridDim.x * 256;
  for (; i < n; i += stride) p[i] = 0u;
}

// 32x32 tile transpose: dst[c][r] = src[r][c].
__global__ __launch_bounds__(256) void transpose_kernel(
    const float* __restrict__ src, float* __restrict__ dst, int R, int C) {
  __shared__ float tile[32][33];
  int r0 = blockIdx.y * 32, c0 = blockIdx.x * 32;
  int tx = threadIdx.x & 31, ty = threadIdx.x >> 5;  // 32 x 8
#pragma unroll
  for (int i = 0; i < 4; ++i)
    tile[ty + i * 8][tx] = src[(size_t)(r0 + ty + i * 8) * C + c0 + tx];
  __syncthreads();
#pragma unroll
  for (int i = 0; i < 4; ++i)
    dst[(size_t)(c0 + ty + i * 8) * R + r0 + tx] = tile[tx][ty + i * 8];
}

// ---------------------------------------------------------------------------
// Merge 8x(top-3) -> global top1 + rivals within GAP_MARGIN -> FLAT flag list.
// ---------------------------------------------------------------------------
__global__ __launch_bounds__(256) void merge_flag_kernel(
    const unsigned long long* __restrict__ cand1,
    const unsigned long long* __restrict__ cand2,
    const unsigned long long* __restrict__ cand3,
    unsigned long long* __restrict__ amaxIdx,
    unsigned* __restrict__ gcount, unsigned* __restrict__ gflag,
    unsigned* __restrict__ clist) {
  int bt = blockIdx.x * 256 + threadIdx.x;  // [0, B*T)
  unsigned long long best = 0ULL;
#pragma unroll
  for (int nb = 0; nb < 8; ++nb) {
    unsigned long long v = cand1[(size_t)bt * 8 + nb];
    if (v > best) best = v;
  }
  amaxIdx[bt] = best;
  float v1 = fdec((unsigned)(best >> 32));
  float thr = v1 - GAP_MARGIN;
  unsigned bestnode = (unsigned)best;

  unsigned nodes[MAXC];
  int cnt = 0;
#pragma unroll
  for (int nb = 0; nb < 8; ++nb) {
    unsigned long long cs[3] = {cand1[(size_t)bt * 8 + nb], cand2[(size_t)bt * 8 + nb],
                                cand3[(size_t)bt * 8 + nb]};
#pragma unroll
    for (int s = 0; s < 3; ++s) {
      float v = fdec((unsigned)(cs[s] >> 32));
      unsigned nd = (unsigned)cs[s];
      if (v >= thr && nd != bestnode && cnt < MAXC) nodes[cnt++] = nd;
    }
  }
  if (cnt > 0) {
    unsigned p = atomicAdd(gcount, 1u);
    if (p < NSLOT) {
      gflag[p] = (unsigned)bt;
      clist[(size_t)bt * 8] = (unsigned)(cnt + 1);
      clist[(size_t)bt * 8 + 1] = bestnode;
      for (int i = 0; i < cnt; ++i) clist[(size_t)bt * 8 + 2 + i] = nodes[i];
    }
  }
}

// ---------------------------------------------------------------------------
// Recheck phase A: k64[fi][d] = sum_c x_t[c] * Wk[d][c]  (f64, exact).
// ---------------------------------------------------------------------------
__global__ __launch_bounds__(256) void recheck_k64(
    const float* __restrict__ x, const float* __restrict__ WkT,
    const unsigned* __restrict__ gcount, const unsigned* __restrict__ gflag,
    double* __restrict__ k64g) {
  __shared__ float xs[CC];
  __shared__ double kpart[64][4];

  const unsigned cnt = min(*gcount, (unsigned)NSLOT);
  const int slot = blockIdx.x >> 3;
  const int dchunk = blockIdx.x & 7;
  if ((unsigned)slot >= cnt) return;
  const int tid = threadIdx.x;

  unsigned bt = gflag[slot];
  int b = bt >> 11, t = bt & (TT - 1);
  const float* xr = x + ((size_t)b * TT + t) * CC;
  xs[tid] = xr[tid];
  xs[tid + 256] = xr[tid + 256];
  __syncthreads();

  const int d = dchunk * 64 + (tid & 63);
  const int part = tid >> 6;
  const int cbase = part * 128;
  double a0 = 0.0, a1 = 0.0;
#pragma unroll 8
  for (int i = 0; i < 64; ++i) {
    int c = cbase + 2 * i;
    a0 = fma((double)WkT[(size_t)c * CC + d], (double)xs[c], a0);
    a1 = fma((double)WkT[(size_t)(c + 1) * CC + d], (double)xs[c + 1], a1);
  }
  kpart[tid & 63][part] = a0 + a1;
  __syncthreads();
  if (tid < 64) {
    double s = (kpart[tid][0] + kpart[tid][1]) + (kpart[tid][2] + kpart[tid][3]);
    k64g[(size_t)slot * CC + dchunk * 64 + tid] = s;
  }
}

// ---------------------------------------------------------------------------
// Recheck phase B: z[fi][t'] = sum_c x[t'][c] * k64[fi][c]  (f64 acc, f32 out).
// ---------------------------------------------------------------------------
__global__ __launch_bounds__(256) void recheck_z(
    const float* __restrict__ x, const unsigned* __restrict__ gcount,
    const unsigned* __restrict__ gflag, const double* __restrict__ k64g,
    float* __restrict__ zg) {
  __shared__ float tile[64][129];
  __shared__ double k64l[CC];
  __shared__ double zp[64][4];

  const unsigned cnt = min(*gcount, (unsigned)NSLOT);
  const int slot = blockIdx.x >> 5;
  const int tchunk = blockIdx.x & 31;
  if ((unsigned)slot >= cnt) return;
  const int tid = threadIdx.x;

  unsigned bt = gflag[slot];
  int b = bt >> 11;
  const float* xb = x + (size_t)b * TT * CC;
  const int tok0 = tchunk * 64;

  k64l[tid] = k64g[(size_t)slot * CC + tid];
  k64l[tid + 256] = k64g[(size_t)slot * CC + tid + 256];

  const int tok = tid >> 2;
  const int part = tid & 3;
  double z0 = 0.0, z1 = 0.0;

  for (int p = 0; p < 4; ++p) {
    __syncthreads();
    int c0 = p * 128;
#pragma unroll
    for (int j = 0; j < 32; ++j) {
      int lin = j * 256 + tid;
      int r = lin >> 7, col = lin & 127;
      tile[r][col] = xb[(size_t)(tok0 + r) * CC + c0 + col];
    }
    __syncthreads();
#pragma unroll
    for (int i = 0; i < 16; ++i) {
      int cl = part * 32 + 2 * i;
      z0 = fma((double)tile[tok][cl], k64l[c0 + cl], z0);
      z1 = fma((double)tile[tok][cl + 1], k64l[c0 + cl + 1], z1);
    }
  }
  zp[tok][part] = z0 + z1;
  __syncthreads();
  if (tid < 64) {
    double z = (zp[tid][0] + zp[tid][1]) + (zp[tid][2] + zp[tid][3]);
    zg[(size_t)slot * TT + tok0 + tid] = (float)z;
  }
}

// ---------------------------------------------------------------------------
// Recheck phase C: sim64(n) = Wq[n,:].z + bq[n]*sum(k64); argmax candidates.
// ---------------------------------------------------------------------------
__global__ __launch_bounds__(256) void recheck_cand(
    const float* __restrict__ Wq, const float* __restrict__ bq,
    const unsigned* __restrict__ gcount, const unsigned* __restrict__ gflag,
    const unsigned* __restrict__ clist, const double* __restrict__ k64g,
    const float* __restrict__ zg, unsigned long long* __restrict__ amaxIdx) {
  __shared__ double red[4];
  __shared__ double ssumS;

  const unsigned cnt = min(*gcount, (unsigned)NSLOT);
  const int slot = blockIdx.x;
  if ((unsigned)slot >= cnt) return;
  const int tid = threadIdx.x;

  unsigned bt = gflag[slot];

  double ps = k64g[(size_t)slot * CC + tid] + k64g[(size_t)slot * CC + tid + 256];
#pragma unroll
  for (int off = 32; off > 0; off >>= 1) ps += __shfl_down(ps, off, 64);
  if ((tid & 63) == 0) red[tid >> 6] = ps;
  __syncthreads();
  if (tid == 0) ssumS = (red[0] + red[1]) + (red[2] + red[3]);
  __syncthreads();
  const double ssum = ssumS;

  const double scl = 0.04419417382415922;
  unsigned ncand = clist[(size_t)bt * 8];
  unsigned long long bestpk = 0ULL;
  double bestv = -1e300;
  for (unsigned ci = 0; ci < ncand; ++ci) {
    unsigned n = clist[(size_t)bt * 8 + 1 + ci];
    const float* wq = Wq + (size_t)n * TT;
    const float* zr = zg + (size_t)slot * TT;
    double a = 0.0;
#pragma unroll
    for (int i = 0; i < TT / 256; ++i) {
      int tp = tid + i * 256;
      a = fma((double)wq[tp], (double)zr[tp], a);
    }
#pragma unroll
    for (int off = 32; off > 0; off >>= 1) a += __shfl_down(a, off, 64);
    if ((tid & 63) == 0) red[tid >> 6] = a;
    __syncthreads();
    double s = ((red[0] + red[1]) + (red[2] + red[3])) + (double)bq[n] * ssum;
    if (s > bestv) {
      bestv = s;
      bestpk = ((unsigned long long)fkey((float)(s * scl)) << 32) | n;
    }
    __syncthreads();
  }
  if (tid == 0) amaxIdx[bt] = bestpk;
}

__global__ __launch_bounds__(256) void node_max_kernel(
    const unsigned long long* __restrict__ amaxIdx, unsigned* __restrict__ Mpack) {
  int i = blockIdx.x * 256 + threadIdx.x;
  unsigned long long pk = amaxIdx[i];
  int b = i >> 11;
  unsigned w = (unsigned)pk;
  atomicMax(&Mpack[b * NNODE + w], (unsigned)(pk >> 32));
}

__global__ __launch_bounds__(256) void node_denom_kernel(
    const unsigned long long* __restrict__ amaxIdx, const unsigned* __restrict__ Mpack,
    float* __restrict__ D, float* __restrict__ att_val) {
  int i = blockIdx.x * 256 + threadIdx.x;
  unsigned long long pk = amaxIdx[i];
  int b = i >> 11;
  unsigned w = (unsigned)pk;
  float amaxf = fdec((unsigned)(pk >> 32));
  float Mf = fdec(Mpack[b * NNODE + w]);
  float e = expf(amaxf - Mf);
  att_val[i] = e;
  atomicAdd(&D[b * NNODE + w], e);
}

__global__ __launch_bounds__(256) void att_write_kernel(
    const unsigned long long* __restrict__ amaxIdx, const float* __restrict__ D,
    float* __restrict__ att_val, float* __restrict__ att_out) {
  int i = blockIdx.x * 256 + threadIdx.x;
  unsigned long long pk = amaxIdx[i];
  int b = i >> 11;
  int t = i & (TT - 1);
  unsigned w = (unsigned)pk;
  float a = att_val[i] / D[b * NNODE + w];
  att_val[i] = a;
  att_out[((size_t)b * NNODE + w) * TT + t] = a;
}

__global__ __launch_bounds__(256) void pv_scatter_kernel(
    const unsigned long long* __restrict__ amaxIdx, const float* __restrict__ att_val,
    const unsigned short* __restrict__ v, float* __restrict__ out0) {
  int bt = blockIdx.x;  // [0, B*T)
  int b = bt >> 11;
  float a = att_val[bt];
  unsigned w = (unsigned)amaxIdx[bt];
  const unsigned short* vr = v + (size_t)bt * CC;
  float* orow = out0 + ((size_t)b * NNODE + w) * CC;
  for (int c = threadIdx.x; c < CC; c += 256)
    atomicAdd(&orow[c], a * bf16_tof(vr[c]));
}

extern "C" void kernel_launch(void* const* d_in, const int* in_sizes, int n_in,
                              void* d_out, int out_size, void* d_ws, size_t ws_size,
                              hipStream_t stream) {
  const float* x = (const float*)d_in[0];     // [B,T,C]  f32
  const float* Wq = (const float*)d_in[1];    // [N,T]
  const float* bq = (const float*)d_in[2];    // [N]
  const float* Wk = (const float*)d_in[3];    // [C,C]
  const float* Wv = (const float*)d_in[4];    // [C,C]
  const float* Wout = (const float*)d_in[5];  // [C,C]
  const float* bout = (const float*)d_in[6];  // [C]

  float* out = (float*)d_out;                      // [B,N,C] f32
  float* att_out = out + (size_t)BB * NNODE * CC;  // [B,N,T] f32

  // Workspace layout: ~111.5 MB total. R = xh/xl region reused post-kv.
  const size_t BNC = (size_t)BB * NNODE * CC;  // 4,194,304
  const size_t BTC = (size_t)BB * TT * CC;     // 8,388,608
  const size_t NT = (size_t)NNODE * TT;        // 2,097,152
  const size_t CC2 = (size_t)CC * CC;          // 262,144
  const size_t BT = (size_t)BB * TT;           // 16,384

  unsigned short* qh = (unsigned short*)d_ws;
  unsigned short* ql = qh + BNC;
  unsigned short* kh = ql + BNC;
  unsigned short* kl = kh + BTC;
  unsigned short* vbuf = kl + BTC;
  unsigned short* Wqh = vbuf + BTC;
  unsigned short* Wql = Wqh + NT;
  unsigned short* Wkh = Wql + NT;
  unsigned short* Wkl = Wkh + CC2;
  unsigned short* Wvh = Wkl + CC2;
  unsigned short* xh = Wvh + CC2;
  unsigned short* xl = xh + BTC;
  unsigned long long* amaxIdx = (unsigned long long*)(xl + BTC);
  unsigned* Mpack = (unsigned*)(amaxIdx + BT);
  float* D = (float*)(Mpack + (size_t)BB * NNODE);
  unsigned* gcount = (unsigned*)(D + (size_t)BB * NNODE);
  float* att_val = (float*)(gcount + 16);
  unsigned* gflag = (unsigned*)(att_val + BT);
  unsigned* clist = gflag + BT;
  // Region R overlays xh/xl (33.5 MB; used after kv; sub-ranges disjoint):
  float* out0 = (float*)xh;                                      // 16.8 MB
  unsigned long long* cand1 = (unsigned long long*)(out0 + BNC); // 1 MB x3
  unsigned long long* cand2 = cand1 + BT * 8;
  unsigned long long* cand3 = cand2 + BT * 8;
  float* WkT = (float*)(cand3 + BT * 8);                         // 1 MB
  double* k64g = (double*)(WkT + CC2);                           // 2 MB
  float* zg = (float*)(k64g + (size_t)NSLOT * CC);               // 4 MB
  // q K-split partials: reuse kh/kl (each BTC u16 = BNC f32; kv runs later)
  float* qp0 = (float*)kh;
  float* qp1 = (float*)kl;

  dim3 blk(256);

  // Pre-split inputs to bf16 hi/lo (one-time; hot loops become pure copies)
  split2_kernel<<<dim3(2048), blk, 0, stream>>>(x, xh, xl, (long long)(BTC / 4));
  split2_kernel<<<dim3(1024), blk, 0, stream>>>(Wq, Wqh, Wql, (long long)(NT / 4));
  split2_kernel<<<dim3(256), blk, 0, stream>>>(Wk, Wkh, Wkl, (long long)(CC2 / 4));
  split1_kernel<<<dim3(256), blk, 0, stream>>>(Wv, Wvh, (long long)(CC2 / 4));

  // Z1: zero Mpack | D | gcount (contiguous)
  fill_zero<<<dim3(64), blk, 0, stream>>>(Mpack, (long long)BB * NNODE * 2 + 16);
  // Z2: zero att region of d_out
  fill_zero<<<dim3(4096), blk, 0, stream>>>((unsigned*)att_out,
                                            (long long)BB * NNODE * TT);

  // q: K-split 128x128 partials (512 blocks) + vectorized add/split
  mfma_q_part<<<dim3(8, NNODE / 128, BB), blk, 0, stream>>>(
      Wqh, Wql, xh, xl, qp0, qp1);
  qadd_kernel<<<dim3((unsigned)(BNC / 1024)), blk, 0, stream>>>(
      qp0, qp1, bq, qh, ql);

  // fused k (split) + v (plain), 64 tokens x 128 dims (x read once)
  mfma_kv_pre<<<dim3(CC / 128, TT / 64, BB), blk, 0, stream>>>(
      xh, xl, Wkh, Wkl, Wvh, kh, kl, vbuf);

  // WkT (in R; safe after kv)
  transpose_kernel<<<dim3(CC / 32, CC / 32), blk, 0, stream>>>(Wk, WkT, CC, CC);

  // sim + top-3 candidates (128 nodes x 64 tokens) -> cand1..3 (in R)
  mfma_sim_pre<<<dim3(TT / 64, NNODE / 128, BB), blk, 0, stream>>>(
      qh, ql, kh, kl, cand1, cand2, cand3);

  // merge -> amaxIdx + flat flag list + candidate lists
  merge_flag_kernel<<<dim3(BB * TT / 256), blk, 0, stream>>>(
      cand1, cand2, cand3, amaxIdx, gcount, gflag, clist);

  // exact f64 recheck: 3 phase-parallel kernels
  recheck_k64<<<dim3(NSLOT * 8), blk, 0, stream>>>(x, WkT, gcount, gflag, k64g);
  recheck_z<<<dim3(NSLOT * 32), blk, 0, stream>>>(x, gcount, gflag, k64g, zg);
  recheck_cand<<<dim3(NSLOT), blk, 0, stream>>>(Wq, bq, gcount, gflag, clist,
                                                k64g, zg, amaxIdx);

  // zero out0 (in R, disjoint from cand/WkT/k64g/zg)
  fill_zero<<<dim3(2048), blk, 0, stream>>>((unsigned*)out0, (long long)BB * NNODE * CC);

  node_max_kernel<<<dim3(BB * TT / 256), blk, 0, stream>>>(amaxIdx, Mpack);
  node_denom_kernel<<<dim3(BB * TT / 256), blk, 0, stream>>>(amaxIdx, Mpack, D, att_val);
  att_write_kernel<<<dim3(BB * TT / 256), blk, 0, stream>>>(amaxIdx, D, att_val, att_out);

  // sparse PV scatter: out0[b,w,c] += att * v[b,t,c]
  pv_scatter_kernel<<<dim3(BB * TT), blk, 0, stream>>>(amaxIdx, att_val, vbuf, out0);

  // out = out0 . Wout^T + bout  (plain MFMA, 64x64 tile)
  mfma_wout<<<dim3(CC / 64, BB * NNODE / 64), blk, 0, stream>>>(
      out0, Wout, out, bout);
}

// Round 22
// 361.904 us; speedup vs baseline: 1.0271x; 1.0271x over previous
//
#include <hip/hip_runtime.h>
#include <hip/hip_bf16.h>
#include <cfloat>

// Problem constants
#define BB 8
#define TT 2048
#define CC 512
#define NNODE 1024

#define GAP_MARGIN 2e-4f  // screening margin (~40 sigma of bf16-split screen noise)
#define MAXC 6            // max rival candidates per flagged token
#define NSLOT 512         // recheck flag capacity

typedef float f32x4 __attribute__((ext_vector_type(4)));
typedef short bf16x8 __attribute__((ext_vector_type(8)));
typedef float float4v __attribute__((ext_vector_type(4)));
typedef unsigned short u16x4 __attribute__((ext_vector_type(4)));
typedef unsigned short u16x8 __attribute__((ext_vector_type(8)));

// ---------------------------------------------------------------------------
__device__ __forceinline__ unsigned fkey(float v) {
  unsigned u = __float_as_uint(v);
  return (u & 0x80000000u) ? ~u : (u | 0x80000000u);
}
__device__ __forceinline__ float fdec(unsigned k) {
  unsigned u = (k & 0x80000000u) ? (k & 0x7FFFFFFFu) : ~k;
  return __uint_as_float(u);
}
__device__ __forceinline__ unsigned short bf16_rn(float f) {
  unsigned u = __float_as_uint(f);
  u += 0x7FFFu + ((u >> 16) & 1u);
  return (unsigned short)(u >> 16);
}
__device__ __forceinline__ float bf16_tof(unsigned short h) {
  return __uint_as_float(((unsigned)h) << 16);
}

// ---------------------------------------------------------------------------
// Pre-split kernels: f32 -> bf16 hi (+ lo residual), vectorized x4.
// ---------------------------------------------------------------------------
__global__ __launch_bounds__(256) void split2_kernel(
    const float* __restrict__ src, unsigned short* __restrict__ hi,
    unsigned short* __restrict__ lo, long long n4) {
  long long i = (long long)blockIdx.x * 256 + threadIdx.x;
  long long stride = (long long)gridDim.x * 256;
  for (; i < n4; i += stride) {
    float4v v = ((const float4v*)src)[i];
    u16x4 h, l;
#pragma unroll
    for (int j = 0; j < 4; ++j) {
      unsigned short hh = bf16_rn(v[j]);
      h[j] = hh;
      l[j] = bf16_rn(v[j] - bf16_tof(hh));
    }
    ((u16x4*)hi)[i] = h;
    ((u16x4*)lo)[i] = l;
  }
}

__global__ __launch_bounds__(256) void split1_kernel(
    const float* __restrict__ src, unsigned short* __restrict__ hi, long long n4) {
  long long i = (long long)blockIdx.x * 256 + threadIdx.x;
  long long stride = (long long)gridDim.x * 256;
  for (; i < n4; i += stride) {
    float4v v = ((const float4v*)src)[i];
    u16x4 h;
#pragma unroll
    for (int j = 0; j < 4; ++j) h[j] = bf16_rn(v[j]);
    ((u16x4*)hi)[i] = h;
  }
}

// ---------------------------------------------------------------------------
// q GEMM K-SPLIT partial (pre-split inputs, 256 threads, 4 waves 2x2,
// 128x128 tile, BK=32): p[kp][b,m,n] = sum_{t in K half kp} Wq[m,t]*x[b,t,n].
// Grid (4 colblk x 2 kpart, NNODE/128, BB) = 512 blocks -> 2/CU.
// ---------------------------------------------------------------------------
__global__ __launch_bounds__(256) void mfma_q_part(
    const unsigned short* __restrict__ Wqh, const unsigned short* __restrict__ Wql,
    const unsigned short* __restrict__ xh, const unsigned short* __restrict__ xl,
    float* __restrict__ p0, float* __restrict__ p1) {
  __shared__ unsigned short Ah[128][40], Al[128][40], Bh[128][40], Bl[128][40];

  const int b = blockIdx.z;
  const unsigned short* xhb = xh + (size_t)b * TT * CC;
  const unsigned short* xlb = xl + (size_t)b * TT * CC;
  const int cb = blockIdx.x & 3;
  const int kp = blockIdx.x >> 2;
  const int m0 = blockIdx.y * 128;
  const int n0 = cb * 128;
  float* dst = kp ? p1 : p0;
  const int tid = threadIdx.x;
  const int l = tid & 63;
  const int wid = tid >> 6;
  const int wy = wid >> 1, wx = wid & 1;
  const int lrow = l & 15, lkb = (l >> 4) * 8;

  f32x4 acc[4][4] = {};

  const int kbeg = kp * (TT / 2), kend = kbeg + (TT / 2);
  for (int k0 = kbeg; k0 < kend; k0 += 32) {
#pragma unroll
    for (int p = 0; p < 2; ++p) {
      int idx = tid + p * 256;
      int ar = idx >> 2, ack = (idx & 3) * 8;
      *(u16x8*)&Ah[ar][ack] = *(const u16x8*)(Wqh + (size_t)(m0 + ar) * TT + k0 + ack);
      *(u16x8*)&Al[ar][ack] = *(const u16x8*)(Wql + (size_t)(m0 + ar) * TT + k0 + ack);
    }
#pragma unroll
    for (int p = 0; p < 2; ++p) {
      int idx = tid + p * 256;
      int nn = idx & 127, kq = idx >> 7;
      u16x8 hv, lv;
#pragma unroll
      for (int j = 0; j < 8; ++j) {
        size_t gi = (size_t)(k0 + kq * 8 + j) * CC + n0 + nn;
        hv[j] = xhb[gi];
        lv[j] = xlb[gi];
      }
      *(u16x8*)&Bh[nn][kq * 8] = hv;
      *(u16x8*)&Bl[nn][kq * 8] = lv;
    }
    __syncthreads();

    bf16x8 ah[4], al[4], bh[4], bl[4];
#pragma unroll
    for (int mf = 0; mf < 4; ++mf) {
      ah[mf] = *(const bf16x8*)&Ah[wy * 64 + mf * 16 + lrow][lkb];
      al[mf] = *(const bf16x8*)&Al[wy * 64 + mf * 16 + lrow][lkb];
    }
#pragma unroll
    for (int nf = 0; nf < 4; ++nf) {
      bh[nf] = *(const bf16x8*)&Bh[wx * 64 + nf * 16 + lrow][lkb];
      bl[nf] = *(const bf16x8*)&Bl[wx * 64 + nf * 16 + lrow][lkb];
    }
#pragma unroll
    for (int mf = 0; mf < 4; ++mf)
#pragma unroll
      for (int nf = 0; nf < 4; ++nf) {
        acc[mf][nf] =
            __builtin_amdgcn_mfma_f32_16x16x32_bf16(ah[mf], bh[nf], acc[mf][nf], 0, 0, 0);
        acc[mf][nf] =
            __builtin_amdgcn_mfma_f32_16x16x32_bf16(ah[mf], bl[nf], acc[mf][nf], 0, 0, 0);
        acc[mf][nf] =
            __builtin_amdgcn_mfma_f32_16x16x32_bf16(al[mf], bh[nf], acc[mf][nf], 0, 0, 0);
      }
    __syncthreads();
  }

#pragma unroll
  for (int mf = 0; mf < 4; ++mf)
#pragma unroll
    for (int r = 0; r < 4; ++r) {
      int m = m0 + wy * 64 + mf * 16 + (l >> 4) * 4 + r;
#pragma unroll
      for (int nf = 0; nf < 4; ++nf) {
        int n = n0 + wx * 64 + nf * 16 + lrow;
        dst[((size_t)b * NNODE + m) * CC + n] = acc[mf][nf][r];
      }
    }
}

// qadd: q = p0 + p1 + bq[m]; write bf16-split qh/ql. Vectorized x4.
__global__ __launch_bounds__(256) void qadd_kernel(
    const float* __restrict__ p0, const float* __restrict__ p1,
    const float* __restrict__ bq,
    unsigned short* __restrict__ qh, unsigned short* __restrict__ ql) {
  size_t i4 = (size_t)blockIdx.x * 256 + threadIdx.x;  // float4 index
  float4v a = ((const float4v*)p0)[i4];
  float4v c = ((const float4v*)p1)[i4];
  int m = (int)(((i4 * 4) / CC) & (NNODE - 1));
  float bias = bq[m];
  u16x4 h, l;
#pragma unroll
  for (int j = 0; j < 4; ++j) {
    float v = a[j] + c[j] + bias;
    unsigned short hh = bf16_rn(v);
    h[j] = hh;
    l[j] = bf16_rn(v - bf16_tof(hh));
  }
  ((u16x4*)qh)[i4] = h;
  ((u16x4*)ql)[i4] = l;
}

// ---------------------------------------------------------------------------
// Fused k (split) + v (plain) projection (256 threads, 64 tokens x 128 dims).
// Grid (CC/128, TT/64, BB) = 1024 blocks.
// ---------------------------------------------------------------------------
__global__ __launch_bounds__(256) void mfma_kv_pre(
    const unsigned short* __restrict__ xh, const unsigned short* __restrict__ xl,
    const unsigned short* __restrict__ Wkh, const unsigned short* __restrict__ Wkl,
    const unsigned short* __restrict__ Wvh,
    unsigned short* __restrict__ kh, unsigned short* __restrict__ kl,
    unsigned short* __restrict__ vout) {
  __shared__ unsigned short Ah[64][40], Al[64][40], Bkh[128][40], Bkl[128][40],
      Bvh[128][40];

  const int b = blockIdx.z;
  const unsigned short* xhb = xh + (size_t)b * TT * CC;
  const unsigned short* xlb = xl + (size_t)b * TT * CC;
  const int m0 = blockIdx.y * 64;
  const int n0 = blockIdx.x * 128;
  const int tid = threadIdx.x;
  const int l = tid & 63;
  const int wid = tid >> 6;
  const int wy = wid >> 1, wx = wid & 1;
  const int lrow = l & 15, lkb = (l >> 4) * 8;
  const int rr = tid >> 2, cq = tid & 3;

  f32x4 acck[2][4] = {}, accv[2][4] = {};

  for (int k0 = 0; k0 < CC; k0 += 32) {
    *(u16x8*)&Ah[rr][cq * 8] = *(const u16x8*)(xhb + (size_t)(m0 + rr) * CC + k0 + cq * 8);
    *(u16x8*)&Al[rr][cq * 8] = *(const u16x8*)(xlb + (size_t)(m0 + rr) * CC + k0 + cq * 8);
#pragma unroll
    for (int p = 0; p < 2; ++p) {
      int idx = tid + p * 256;
      int r = idx >> 2, ck = (idx & 3) * 8;
      *(u16x8*)&Bkh[r][ck] = *(const u16x8*)(Wkh + (size_t)(n0 + r) * CC + k0 + ck);
      *(u16x8*)&Bkl[r][ck] = *(const u16x8*)(Wkl + (size_t)(n0 + r) * CC + k0 + ck);
      *(u16x8*)&Bvh[r][ck] = *(const u16x8*)(Wvh + (size_t)(n0 + r) * CC + k0 + ck);
    }
    __syncthreads();

    bf16x8 ah[2], al[2], bkh4[4], bkl4[4], bvh4[4];
#pragma unroll
    for (int mf = 0; mf < 2; ++mf) {
      ah[mf] = *(const bf16x8*)&Ah[wy * 32 + mf * 16 + lrow][lkb];
      al[mf] = *(const bf16x8*)&Al[wy * 32 + mf * 16 + lrow][lkb];
    }
#pragma unroll
    for (int nf = 0; nf < 4; ++nf) {
      bkh4[nf] = *(const bf16x8*)&Bkh[wx * 64 + nf * 16 + lrow][lkb];
      bkl4[nf] = *(const bf16x8*)&Bkl[wx * 64 + nf * 16 + lrow][lkb];
      bvh4[nf] = *(const bf16x8*)&Bvh[wx * 64 + nf * 16 + lrow][lkb];
    }
#pragma unroll
    for (int mf = 0; mf < 2; ++mf)
#pragma unroll
      for (int nf = 0; nf < 4; ++nf) {
        acck[mf][nf] =
            __builtin_amdgcn_mfma_f32_16x16x32_bf16(ah[mf], bkh4[nf], acck[mf][nf], 0, 0, 0);
        acck[mf][nf] =
            __builtin_amdgcn_mfma_f32_16x16x32_bf16(ah[mf], bkl4[nf], acck[mf][nf], 0, 0, 0);
        acck[mf][nf] =
            __builtin_amdgcn_mfma_f32_16x16x32_bf16(al[mf], bkh4[nf], acck[mf][nf], 0, 0, 0);
        accv[mf][nf] =
            __builtin_amdgcn_mfma_f32_16x16x32_bf16(ah[mf], bvh4[nf], accv[mf][nf], 0, 0, 0);
      }
    __syncthreads();
  }

#pragma unroll
  for (int mf = 0; mf < 2; ++mf)
#pragma unroll
    for (int r = 0; r < 4; ++r) {
      int m = m0 + wy * 32 + mf * 16 + (l >> 4) * 4 + r;
#pragma unroll
      for (int nf = 0; nf < 4; ++nf) {
        int n = n0 + wx * 64 + nf * 16 + lrow;
        size_t off = ((size_t)b * TT + m) * CC + n;
        float kvv = acck[mf][nf][r];
        unsigned short h = bf16_rn(kvv);
        kh[off] = h;
        kl[off] = bf16_rn(kvv - bf16_tof(h));
        vout[off] = bf16_rn(accv[mf][nf][r]);
      }
    }
}

// ---------------------------------------------------------------------------
// sim (pre-split q,k; no store) + top-3 candidates. 128 nodes x 64 tokens.
// Round-20 measured-best epilogue (VGPR 64, occupancy 40%).
// ---------------------------------------------------------------------------
__global__ __launch_bounds__(256) void mfma_sim_pre(
    const unsigned short* __restrict__ qh, const unsigned short* __restrict__ ql,
    const unsigned short* __restrict__ kh, const unsigned short* __restrict__ kl,
    unsigned long long* __restrict__ cand1, unsigned long long* __restrict__ cand2,
    unsigned long long* __restrict__ cand3) {
  __shared__ unsigned short Ah[128][40], Al[128][40], Bh[64][40], Bl[64][40];
  __shared__ unsigned long long c1[64], c2[64], c3[64];

  const int b = blockIdx.z;
  const unsigned short* qhb = qh + (size_t)b * NNODE * CC;
  const unsigned short* qlb = ql + (size_t)b * NNODE * CC;
  const unsigned short* khb = kh + (size_t)b * TT * CC;
  const unsigned short* klb = kl + (size_t)b * TT * CC;
  const int n0 = blockIdx.y * 128;  // nodes
  const int t0 = blockIdx.x * 64;   // tokens
  const int tid = threadIdx.x;
  const int l = tid & 63;
  const int wid = tid >> 6;
  const int wy = wid >> 1, wx = wid & 1;
  const int lrow = l & 15, lkb = (l >> 4) * 8;
  const int br = tid >> 2, bck = (tid & 3) * 8;

  if (tid < 64) { c1[tid] = 0ULL; c2[tid] = 0ULL; c3[tid] = 0ULL; }

  f32x4 acc[4][2] = {};

  for (int k0 = 0; k0 < CC; k0 += 32) {
#pragma unroll
    for (int p = 0; p < 2; ++p) {
      int idx = tid + p * 256;
      int r = idx >> 2, ck = (idx & 3) * 8;
      *(u16x8*)&Ah[r][ck] = *(const u16x8*)(qhb + (size_t)(n0 + r) * CC + k0 + ck);
      *(u16x8*)&Al[r][ck] = *(const u16x8*)(qlb + (size_t)(n0 + r) * CC + k0 + ck);
    }
    if (br < 64) {
      *(u16x8*)&Bh[br][bck] = *(const u16x8*)(khb + (size_t)(t0 + br) * CC + k0 + bck);
      *(u16x8*)&Bl[br][bck] = *(const u16x8*)(klb + (size_t)(t0 + br) * CC + k0 + bck);
    }
    __syncthreads();

    bf16x8 ah[4], al[4], bh[2], bl[2];
#pragma unroll
    for (int mf = 0; mf < 4; ++mf) {
      ah[mf] = *(const bf16x8*)&Ah[wy * 64 + mf * 16 + lrow][lkb];
      al[mf] = *(const bf16x8*)&Al[wy * 64 + mf * 16 + lrow][lkb];
    }
#pragma unroll
    for (int nf = 0; nf < 2; ++nf) {
      bh[nf] = *(const bf16x8*)&Bh[wx * 32 + nf * 16 + lrow][lkb];
      bl[nf] = *(const bf16x8*)&Bl[wx * 32 + nf * 16 + lrow][lkb];
    }
#pragma unroll
    for (int mf = 0; mf < 4; ++mf)
#pragma unroll
      for (int nf = 0; nf < 2; ++nf) {
        acc[mf][nf] =
            __builtin_amdgcn_mfma_f32_16x16x32_bf16(ah[mf], bh[nf], acc[mf][nf], 0, 0, 0);
        acc[mf][nf] =
            __builtin_amdgcn_mfma_f32_16x16x32_bf16(ah[mf], bl[nf], acc[mf][nf], 0, 0, 0);
        acc[mf][nf] =
            __builtin_amdgcn_mfma_f32_16x16x32_bf16(al[mf], bh[nf], acc[mf][nf], 0, 0, 0);
      }
    __syncthreads();
  }

  const float scl = 0.04419417382415922f;
#pragma unroll
  for (int nf = 0; nf < 2; ++nf) {
    int tcol = wx * 32 + nf * 16 + lrow;
    unsigned long long m = 0ULL;
#pragma unroll
    for (int mf = 0; mf < 4; ++mf)
#pragma unroll
      for (int r = 0; r < 4; ++r) {
        unsigned node = (unsigned)(n0 + wy * 64 + mf * 16 + (l >> 4) * 4 + r);
        unsigned long long pk =
            ((unsigned long long)fkey(acc[mf][nf][r] * scl) << 32) | node;
        if (pk > m) m = pk;
      }
    atomicMax(&c1[tcol], m);
  }
  __syncthreads();
#pragma unroll
  for (int nf = 0; nf < 2; ++nf) {
    int tcol = wx * 32 + nf * 16 + lrow;
    unsigned w1 = (unsigned)c1[tcol];
    unsigned long long m = 0ULL;
#pragma unroll
    for (int mf = 0; mf < 4; ++mf)
#pragma unroll
      for (int r = 0; r < 4; ++r) {
        unsigned node = (unsigned)(n0 + wy * 64 + mf * 16 + (l >> 4) * 4 + r);
        if (node == w1) continue;
        unsigned long long pk =
            ((unsigned long long)fkey(acc[mf][nf][r] * scl) << 32) | node;
        if (pk > m) m = pk;
      }
    if (m) atomicMax(&c2[tcol], m);
  }
  __syncthreads();
#pragma unroll
  for (int nf = 0; nf < 2; ++nf) {
    int tcol = wx * 32 + nf * 16 + lrow;
    unsigned w1 = (unsigned)c1[tcol];
    unsigned w2 = (unsigned)c2[tcol];
    unsigned long long m = 0ULL;
#pragma unroll
    for (int mf = 0; mf < 4; ++mf)
#pragma unroll
      for (int r = 0; r < 4; ++r) {
        unsigned node = (unsigned)(n0 + wy * 64 + mf * 16 + (l >> 4) * 4 + r);
        if (node == w1 || node == w2) continue;
        unsigned long long pk =
            ((unsigned long long)fkey(acc[mf][nf][r] * scl) << 32) | node;
        if (pk > m) m = pk;
      }
    if (m) atomicMax(&c3[tcol], m);
  }
  __syncthreads();
  if (tid < 64) {
    size_t base = ((size_t)b * TT + (t0 + tid)) * 8 + blockIdx.y;
    cand1[base] = c1[tid];
    cand2[base] = c2[tid];
    cand3[base] = c3[tid];
  }
}

// ---------------------------------------------------------------------------
// Wout GEMM (f32 inputs, plain bf16 MFMA, 256 threads, 64x64 tile).
// ---------------------------------------------------------------------------
__global__ __launch_bounds__(256) void mfma_wout(
    const float* __restrict__ A, const float* __restrict__ Bm,
    float* __restrict__ Cp, const float* __restrict__ bias) {
  __shared__ unsigned short Ah[64][40], Bh[64][40];
  const int m0 = blockIdx.y * 64;
  const int n0 = blockIdx.x * 64;
  const int tid = threadIdx.x;
  const int l = tid & 63;
  const int wid = tid >> 6;
  const int wy = wid >> 1, wx = wid & 1;
  const int lrow = l & 15, lkb = (l >> 4) * 8;

  f32x4 acc[2][2] = {};

  for (int k0 = 0; k0 < CC; k0 += 32) {
#pragma unroll
    for (int p = 0; p < 2; ++p) {
      int idx = tid + p * 256;
      int r = idx >> 3, c = (idx & 7) * 4;
      float4v va = *(const float4v*)(A + (size_t)(m0 + r) * CC + k0 + c);
      float4v vb = *(const float4v*)(Bm + (size_t)(n0 + r) * CC + k0 + c);
#pragma unroll
      for (int i = 0; i < 4; ++i) {
        Ah[r][c + i] = bf16_rn(va[i]);
        Bh[r][c + i] = bf16_rn(vb[i]);
      }
    }
    __syncthreads();

    bf16x8 ah[2], bh[2];
#pragma unroll
    for (int mf = 0; mf < 2; ++mf)
      ah[mf] = *(const bf16x8*)&Ah[wy * 32 + mf * 16 + lrow][lkb];
#pragma unroll
    for (int nf = 0; nf < 2; ++nf)
      bh[nf] = *(const bf16x8*)&Bh[wx * 32 + nf * 16 + lrow][lkb];
#pragma unroll
    for (int mf = 0; mf < 2; ++mf)
#pragma unroll
      for (int nf = 0; nf < 2; ++nf)
        acc[mf][nf] =
            __builtin_amdgcn_mfma_f32_16x16x32_bf16(ah[mf], bh[nf], acc[mf][nf], 0, 0, 0);
    __syncthreads();
  }

#pragma unroll
  for (int mf = 0; mf < 2; ++mf)
#pragma unroll
    for (int r = 0; r < 4; ++r) {
      int m = m0 + wy * 32 + mf * 16 + (l >> 4) * 4 + r;
#pragma unroll
      for (int nf = 0; nf < 2; ++nf) {
        int n = n0 + wx * 32 + nf * 16 + lrow;
        Cp[(size_t)m * CC + n] = acc[mf][nf][r] + bias[n];
      }
    }
}

__global__ __launch_bounds__(256) void fill_zero(unsigned* __restrict__ p, long long n) {
  long long i = (long long)blockIdx.x * 256 + threadIdx.x;
  long long stride = (long long)gridDim.x * 256;
  for (; i < n; i += stride) p[i] = 0u;
}

// 32x32 tile transpose: dst[c][r] = src[r][c].
__global__ __launch_bounds__(256) void transpose_kernel(
    const float* __restrict__ src, float* __restrict__ dst, int R, int C) {
  __shared__ float tile[32][33];
  int r0 = blockIdx.y * 32, c0 = blockIdx.x * 32;
  int tx = threadIdx.x & 31, ty = threadIdx.x >> 5;  // 32 x 8
#pragma unroll
  for (int i = 0; i < 4; ++i)
    tile[ty + i * 8][tx] = src[(size_t)(r0 + ty + i * 8) * C + c0 + tx];
  __syncthreads();
#pragma unroll
  for (int i = 0; i < 4; ++i)
    dst[(size_t)(c0 + ty + i * 8) * R + r0 + tx] = tile[tx][ty + i * 8];
}

// ---------------------------------------------------------------------------
// Merge 8x(top-3) -> global top1 + rivals within GAP_MARGIN -> FLAT flag list.
// ---------------------------------------------------------------------------
__global__ __launch_bounds__(256) void merge_flag_kernel(
    const unsigned long long* __restrict__ cand1,
    const unsigned long long* __restrict__ cand2,
    const unsigned long long* __restrict__ cand3,
    unsigned long long* __restrict__ amaxIdx,
    unsigned* __restrict__ gcount, unsigned* __restrict__ gflag,
    unsigned* __restrict__ clist) {
  int bt = blockIdx.x * 256 + threadIdx.x;  // [0, B*T)
  unsigned long long best = 0ULL;
#pragma unroll
  for (int nb = 0; nb < 8; ++nb) {
    unsigned long long v = cand1[(size_t)bt * 8 + nb];
    if (v > best) best = v;
  }
  amaxIdx[bt] = best;
  float v1 = fdec((unsigned)(best >> 32));
  float thr = v1 - GAP_MARGIN;
  unsigned bestnode = (unsigned)best;

  unsigned nodes[MAXC];
  int cnt = 0;
#pragma unroll
  for (int nb = 0; nb < 8; ++nb) {
    unsigned long long cs[3] = {cand1[(size_t)bt * 8 + nb], cand2[(size_t)bt * 8 + nb],
                                cand3[(size_t)bt * 8 + nb]};
#pragma unroll
    for (int s = 0; s < 3; ++s) {
      float v = fdec((unsigned)(cs[s] >> 32));
      unsigned nd = (unsigned)cs[s];
      if (v >= thr && nd != bestnode && cnt < MAXC) nodes[cnt++] = nd;
    }
  }
  if (cnt > 0) {
    unsigned p = atomicAdd(gcount, 1u);
    if (p < NSLOT) {
      gflag[p] = (unsigned)bt;
      clist[(size_t)bt * 8] = (unsigned)(cnt + 1);
      clist[(size_t)bt * 8 + 1] = bestnode;
      for (int i = 0; i < cnt; ++i) clist[(size_t)bt * 8 + 2 + i] = nodes[i];
    }
  }
}

// ---------------------------------------------------------------------------
// Recheck phase A: k64[fi][d] = sum_c x_t[c] * Wk[d][c]  (f64, exact).
// ---------------------------------------------------------------------------
__global__ __launch_bounds__(256) void recheck_k64(
    const float* __restrict__ x, const float* __restrict__ WkT,
    const unsigned* __restrict__ gcount, const unsigned* __restrict__ gflag,
    double* __restrict__ k64g) {
  __shared__ float xs[CC];
  __shared__ double kpart[64][4];

  const unsigned cnt = min(*gcount, (unsigned)NSLOT);
  const int slot = blockIdx.x >> 3;
  const int dchunk = blockIdx.x & 7;
  if ((unsigned)slot >= cnt) return;
  const int tid = threadIdx.x;

  unsigned bt = gflag[slot];
  int b = bt >> 11, t = bt & (TT - 1);
  const float* xr = x + ((size_t)b * TT + t) * CC;
  xs[tid] = xr[tid];
  xs[tid + 256] = xr[tid + 256];
  __syncthreads();

  const int d = dchunk * 64 + (tid & 63);
  const int part = tid >> 6;
  const int cbase = part * 128;
  double a0 = 0.0, a1 = 0.0;
#pragma unroll 8
  for (int i = 0; i < 64; ++i) {
    int c = cbase + 2 * i;
    a0 = fma((double)WkT[(size_t)c * CC + d], (double)xs[c], a0);
    a1 = fma((double)WkT[(size_t)(c + 1) * CC + d], (double)xs[c + 1], a1);
  }
  kpart[tid & 63][part] = a0 + a1;
  __syncthreads();
  if (tid < 64) {
    double s = (kpart[tid][0] + kpart[tid][1]) + (kpart[tid][2] + kpart[tid][3]);
    k64g[(size_t)slot * CC + dchunk * 64 + tid] = s;
  }
}

// ---------------------------------------------------------------------------
// Recheck phase B: z[fi][t'] = sum_c x[t'][c] * k64[fi][c]  (f64 acc, f32 out).
// ---------------------------------------------------------------------------
__global__ __launch_bounds__(256) void recheck_z(
    const float* __restrict__ x, const unsigned* __restrict__ gcount,
    const unsigned* __restrict__ gflag, const double* __restrict__ k64g,
    float* __restrict__ zg) {
  __shared__ float tile[64][129];
  __shared__ double k64l[CC];
  __shared__ double zp[64][4];

  const unsigned cnt = min(*gcount, (unsigned)NSLOT);
  const int slot = blockIdx.x >> 5;
  const int tchunk = blockIdx.x & 31;
  if ((unsigned)slot >= cnt) return;
  const int tid = threadIdx.x;

  unsigned bt = gflag[slot];
  int b = bt >> 11;
  const float* xb = x + (size_t)b * TT * CC;
  const int tok0 = tchunk * 64;

  k64l[tid] = k64g[(size_t)slot * CC + tid];
  k64l[tid + 256] = k64g[(size_t)slot * CC + tid + 256];

  const int tok = tid >> 2;
  const int part = tid & 3;
  double z0 = 0.0, z1 = 0.0;

  for (int p = 0; p < 4; ++p) {
    __syncthreads();
    int c0 = p * 128;
#pragma unroll
    for (int j = 0; j < 32; ++j) {
      int lin = j * 256 + tid;
      int r = lin >> 7, col = lin & 127;
      tile[r][col] = xb[(size_t)(tok0 + r) * CC + c0 + col];
    }
    __syncthreads();
#pragma unroll
    for (int i = 0; i < 16; ++i) {
      int cl = part * 32 + 2 * i;
      z0 = fma((double)tile[tok][cl], k64l[c0 + cl], z0);
      z1 = fma((double)tile[tok][cl + 1], k64l[c0 + cl + 1], z1);
    }
  }
  zp[tok][part] = z0 + z1;
  __syncthreads();
  if (tid < 64) {
    double z = (zp[tid][0] + zp[tid][1]) + (zp[tid][2] + zp[tid][3]);
    zg[(size_t)slot * TT + tok0 + tid] = (float)z;
  }
}

// ---------------------------------------------------------------------------
// Recheck phase C: sim64(n) = Wq[n,:].z + bq[n]*sum(k64); argmax candidates.
// ---------------------------------------------------------------------------
__global__ __launch_bounds__(256) void recheck_cand(
    const float* __restrict__ Wq, const float* __restrict__ bq,
    const unsigned* __restrict__ gcount, const unsigned* __restrict__ gflag,
    const unsigned* __restrict__ clist, const double* __restrict__ k64g,
    const float* __restrict__ zg, unsigned long long* __restrict__ amaxIdx) {
  __shared__ double red[4];
  __shared__ double ssumS;

  const unsigned cnt = min(*gcount, (unsigned)NSLOT);
  const int slot = blockIdx.x;
  if ((unsigned)slot >= cnt) return;
  const int tid = threadIdx.x;

  unsigned bt = gflag[slot];

  double ps = k64g[(size_t)slot * CC + tid] + k64g[(size_t)slot * CC + tid + 256];
#pragma unroll
  for (int off = 32; off > 0; off >>= 1) ps += __shfl_down(ps, off, 64);
  if ((tid & 63) == 0) red[tid >> 6] = ps;
  __syncthreads();
  if (tid == 0) ssumS = (red[0] + red[1]) + (red[2] + red[3]);
  __syncthreads();
  const double ssum = ssumS;

  const double scl = 0.04419417382415922;
  unsigned ncand = clist[(size_t)bt * 8];
  unsigned long long bestpk = 0ULL;
  double bestv = -1e300;
  for (unsigned ci = 0; ci < ncand; ++ci) {
    unsigned n = clist[(size_t)bt * 8 + 1 + ci];
    const float* wq = Wq + (size_t)n * TT;
    const float* zr = zg + (size_t)slot * TT;
    double a = 0.0;
#pragma unroll
    for (int i = 0; i < TT / 256; ++i) {
      int tp = tid + i * 256;
      a = fma((double)wq[tp], (double)zr[tp], a);
    }
#pragma unroll
    for (int off = 32; off > 0; off >>= 1) a += __shfl_down(a, off, 64);
    if ((tid & 63) == 0) red[tid >> 6] = a;
    __syncthreads();
    double s = ((red[0] + red[1]) + (red[2] + red[3])) + (double)bq[n] * ssum;
    if (s > bestv) {
      bestv = s;
      bestpk = ((unsigned long long)fkey((float)(s * scl)) << 32) | n;
    }
    __syncthreads();
  }
  if (tid == 0) amaxIdx[bt] = bestpk;
}

__global__ __launch_bounds__(256) void node_max_kernel(
    const unsigned long long* __restrict__ amaxIdx, unsigned* __restrict__ Mpack) {
  int i = blockIdx.x * 256 + threadIdx.x;
  unsigned long long pk = amaxIdx[i];
  int b = i >> 11;
  unsigned w = (unsigned)pk;
  atomicMax(&Mpack[b * NNODE + w], (unsigned)(pk >> 32));
}

__global__ __launch_bounds__(256) void node_denom_kernel(
    const unsigned long long* __restrict__ amaxIdx, const unsigned* __restrict__ Mpack,
    float* __restrict__ D, float* __restrict__ att_val) {
  int i = blockIdx.x * 256 + threadIdx.x;
  unsigned long long pk = amaxIdx[i];
  int b = i >> 11;
  unsigned w = (unsigned)pk;
  float amaxf = fdec((unsigned)(pk >> 32));
  float Mf = fdec(Mpack[b * NNODE + w]);
  float e = expf(amaxf - Mf);
  att_val[i] = e;
  atomicAdd(&D[b * NNODE + w], e);
}

__global__ __launch_bounds__(256) void att_write_kernel(
    const unsigned long long* __restrict__ amaxIdx, const float* __restrict__ D,
    float* __restrict__ att_val, float* __restrict__ att_out) {
  int i = blockIdx.x * 256 + threadIdx.x;
  unsigned long long pk = amaxIdx[i];
  int b = i >> 11;
  int t = i & (TT - 1);
  unsigned w = (unsigned)pk;
  float a = att_val[i] / D[b * NNODE + w];
  att_val[i] = a;
  att_out[((size_t)b * NNODE + w) * TT + t] = a;
}

__global__ __launch_bounds__(256) void pv_scatter_kernel(
    const unsigned long long* __restrict__ amaxIdx, const float* __restrict__ att_val,
    const unsigned short* __restrict__ v, float* __restrict__ out0) {
  int bt = blockIdx.x;  // [0, B*T)
  int b = bt >> 11;
  float a = att_val[bt];
  unsigned w = (unsigned)amaxIdx[bt];
  const unsigned short* vr = v + (size_t)bt * CC;
  float* orow = out0 + ((size_t)b * NNODE + w) * CC;
  for (int c = threadIdx.x; c < CC; c += 256)
    atomicAdd(&orow[c], a * bf16_tof(vr[c]));
}

extern "C" void kernel_launch(void* const* d_in, const int* in_sizes, int n_in,
                              void* d_out, int out_size, void* d_ws, size_t ws_size,
                              hipStream_t stream) {
  const float* x = (const float*)d_in[0];     // [B,T,C]  f32
  const float* Wq = (const float*)d_in[1];    // [N,T]
  const float* bq = (const float*)d_in[2];    // [N]
  const float* Wk = (const float*)d_in[3];    // [C,C]
  const float* Wv = (const float*)d_in[4];    // [C,C]
  const float* Wout = (const float*)d_in[5];  // [C,C]
  const float* bout = (const float*)d_in[6];  // [C]

  float* out = (float*)d_out;                      // [B,N,C] f32
  float* att_out = out + (size_t)BB * NNODE * CC;  // [B,N,T] f32

  // Workspace layout: ~111.5 MB total. R = xh/xl region reused post-kv.
  const size_t BNC = (size_t)BB * NNODE * CC;  // 4,194,304
  const size_t BTC = (size_t)BB * TT * CC;     // 8,388,608
  const size_t NT = (size_t)NNODE * TT;        // 2,097,152
  const size_t CC2 = (size_t)CC * CC;          // 262,144
  const size_t BT = (size_t)BB * TT;           // 16,384

  unsigned short* qh = (unsigned short*)d_ws;
  unsigned short* ql = qh + BNC;
  unsigned short* kh = ql + BNC;
  unsigned short* kl = kh + BTC;
  unsigned short* vbuf = kl + BTC;
  unsigned short* Wqh = vbuf + BTC;
  unsigned short* Wql = Wqh + NT;
  unsigned short* Wkh = Wql + NT;
  unsigned short* Wkl = Wkh + CC2;
  unsigned short* Wvh = Wkl + CC2;
  unsigned short* xh = Wvh + CC2;
  unsigned short* xl = xh + BTC;
  unsigned long long* amaxIdx = (unsigned long long*)(xl + BTC);
  unsigned* Mpack = (unsigned*)(amaxIdx + BT);
  float* D = (float*)(Mpack + (size_t)BB * NNODE);
  unsigned* gcount = (unsigned*)(D + (size_t)BB * NNODE);
  float* att_val = (float*)(gcount + 16);
  unsigned* gflag = (unsigned*)(att_val + BT);
  unsigned* clist = gflag + BT;
  // Region R overlays xh/xl (33.5 MB; used after kv; sub-ranges disjoint):
  float* out0 = (float*)xh;                                      // 16.8 MB
  unsigned long long* cand1 = (unsigned long long*)(out0 + BNC); // 1 MB x3
  unsigned long long* cand2 = cand1 + BT * 8;
  unsigned long long* cand3 = cand2 + BT * 8;
  float* WkT = (float*)(cand3 + BT * 8);                         // 1 MB
  double* k64g = (double*)(WkT + CC2);                           // 2 MB
  float* zg = (float*)(k64g + (size_t)NSLOT * CC);               // 4 MB
  // q K-split partials: reuse kh/kl (each BTC u16 = BNC f32; kv runs later)
  float* qp0 = (float*)kh;
  float* qp1 = (float*)kl;

  dim3 blk(256);

  // Pre-split inputs to bf16 hi/lo (one-time; hot loops become pure copies)
  split2_kernel<<<dim3(2048), blk, 0, stream>>>(x, xh, xl, (long long)(BTC / 4));
  split2_kernel<<<dim3(1024), blk, 0, stream>>>(Wq, Wqh, Wql, (long long)(NT / 4));
  split2_kernel<<<dim3(256), blk, 0, stream>>>(Wk, Wkh, Wkl, (long long)(CC2 / 4));
  split1_kernel<<<dim3(256), blk, 0, stream>>>(Wv, Wvh, (long long)(CC2 / 4));

  // Z1: zero Mpack | D | gcount (contiguous)
  fill_zero<<<dim3(64), blk, 0, stream>>>(Mpack, (long long)BB * NNODE * 2 + 16);
  // Z2: zero att region of d_out
  fill_zero<<<dim3(4096), blk, 0, stream>>>((unsigned*)att_out,
                                            (long long)BB * NNODE * TT);

  // q: K-split 128x128 partials (512 blocks) + vectorized add/split
  mfma_q_part<<<dim3(8, NNODE / 128, BB), blk, 0, stream>>>(
      Wqh, Wql, xh, xl, qp0, qp1);
  qadd_kernel<<<dim3((unsigned)(BNC / 1024)), blk, 0, stream>>>(
      qp0, qp1, bq, qh, ql);

  // fused k (split) + v (plain), 64 tokens x 128 dims (x read once)
  mfma_kv_pre<<<dim3(CC / 128, TT / 64, BB), blk, 0, stream>>>(
      xh, xl, Wkh, Wkl, Wvh, kh, kl, vbuf);

  // WkT (in R; safe after kv)
  transpose_kernel<<<dim3(CC / 32, CC / 32), blk, 0, stream>>>(Wk, WkT, CC, CC);

  // sim + top-3 candidates (128 nodes x 64 tokens) -> cand1..3 (in R)
  mfma_sim_pre<<<dim3(TT / 64, NNODE / 128, BB), blk, 0, stream>>>(
      qh, ql, kh, kl, cand1, cand2, cand3);

  // merge -> amaxIdx + flat flag list + candidate lists
  merge_flag_kernel<<<dim3(BB * TT / 256), blk, 0, stream>>>(
      cand1, cand2, cand3, amaxIdx, gcount, gflag, clist);

  // exact f64 recheck: 3 phase-parallel kernels
  recheck_k64<<<dim3(NSLOT * 8), blk, 0, stream>>>(x, WkT, gcount, gflag, k64g);
  recheck_z<<<dim3(NSLOT * 32), blk, 0, stream>>>(x, gcount, gflag, k64g, zg);
  recheck_cand<<<dim3(NSLOT), blk, 0, stream>>>(Wq, bq, gcount, gflag, clist,
                                                k64g, zg, amaxIdx);

  // zero out0 (in R, disjoint from cand/WkT/k64g/zg)
  fill_zero<<<dim3(2048), blk, 0, stream>>>((unsigned*)out0, (long long)BB * NNODE * CC);

  node_max_kernel<<<dim3(BB * TT / 256), blk, 0, stream>>>(amaxIdx, Mpack);
  node_denom_kernel<<<dim3(BB * TT / 256), blk, 0, stream>>>(amaxIdx, Mpack, D, att_val);
  att_write_kernel<<<dim3(BB * TT / 256), blk, 0, stream>>>(amaxIdx, D, att_val, att_out);

  // sparse PV scatter: out0[b,w,c] += att * v[b,t,c]
  pv_scatter_kernel<<<dim3(BB * TT), blk, 0, stream>>>(amaxIdx, att_val, vbuf, out0);

  // out = out0 . Wout^T + bout  (plain MFMA, 64x64 tile)
  mfma_wout<<<dim3(CC / 64, BB * NNODE / 64), blk, 0, stream>>>(
      out0, Wout, out, bout);
}